// Round 7
// baseline (503.941 us; speedup 1.0000x reference)
//
#include <hip/hip_runtime.h>

// 7x7 conv, stride 1, pad 3, on 64 x 512 x 512 fp32 (single channel).
// out[n,y,x] = sum_{ky,kx} x[n, y+ky-3, x+kx-3] * w[ky,kx]
//
// R6: streaming W4R4 (no LDS, no barrier), with sched_barrier(0) fencing each
// input row so the compiler cannot hoist all 30 loads and spill (R3/R5 failure:
// WRITE_SIZE 5x output = scratch traffic). Live set ~45 VGPR -> fits the
// 64-VGPR / 8-waves-per-EU occupancy point.

#define IMG_W 512
#define IMG_H 512
#define NIMG  64
#define ROWS  4       // output rows per thread
#define HALO  3

__global__ __launch_bounds__(256, 8) void conv7x7_kernel(
    const float* __restrict__ x,
    const float* __restrict__ wgt,
    float* __restrict__ out)
{
    const int tid = threadIdx.x;
    // 128 threads across x (128*4 = 512 = full row), 2 thread-rows per block.
    const int ox = (tid & 127) * 4;
    const int ty = tid >> 7;
    const int oy = (blockIdx.x * 2 + ty) * ROWS;
    const int n  = blockIdx.y;

    const float* img = x + (size_t)n * (IMG_W * IMG_H);

    // weights: wave-uniform -> SGPRs (statically indexed after unroll)
    float w[49];
    #pragma unroll
    for (int i = 0; i < 49; ++i) w[i] = wgt[i];

    // x-border predicates (all-or-nothing per aligned float4):
    // left  f4 = cols [ox-4, ox)   -> OOB only when ox == 0
    // right f4 = cols [ox+4, ox+8) -> OOB only when ox == 508
    const bool lval = (ox != 0);
    const bool rval = (ox + 7 < IMG_W);

    float acc[ROWS][4] = {};
    const float4 z4 = make_float4(0.f, 0.f, 0.f, 0.f);

    #pragma unroll
    for (int r = 0; r < ROWS + 2 * HALO; ++r) {   // 10 input rows
        const int gy = oy - HALO + r;
        const bool yv = (unsigned)gy < IMG_H;
        const float* rp = &img[(size_t)gy * IMG_W + ox];
        const float4 a  = (yv && lval) ? *(const float4*)(rp - 4) : z4;
        const float4 b  = yv           ? *(const float4*)(rp)     : z4;
        const float4 c4 = (yv && rval) ? *(const float4*)(rp + 4) : z4;
        // row[t] = input col ox-4+t (t=0..11 contiguous).
        // Output col ox+c, tap kx needs col ox+c+kx-3 -> t = c+kx+1.
        const float row[12] = { a.x, a.y, a.z, a.w,
                                b.x, b.y, b.z, b.w,
                                c4.x, c4.y, c4.z, c4.w };
        #pragma unroll
        for (int j = 0; j < ROWS; ++j) {
            const int ky = r - j;
            if (ky >= 0 && ky < 7) {
                #pragma unroll
                for (int kx = 0; kx < 7; ++kx) {
                    const float wv = w[ky * 7 + kx];
                    #pragma unroll
                    for (int c = 0; c < 4; ++c)
                        acc[j][c] = fmaf(row[c + kx + 1], wv, acc[j][c]);
                }
            }
        }
        // Fence: loads of row r+1 may not hoist above the FMAs of row r.
        // Keeps live registers ~45 -> no scratch spill at the 64-VGPR point.
        __builtin_amdgcn_sched_barrier(0);
    }

    float* o = out + (size_t)n * (IMG_W * IMG_H);
    #pragma unroll
    for (int j = 0; j < ROWS; ++j) {
        float4 v = make_float4(acc[j][0], acc[j][1], acc[j][2], acc[j][3]);
        *(float4*)&o[(size_t)(oy + j) * IMG_W + ox] = v;
    }
}

extern "C" void kernel_launch(void* const* d_in, const int* in_sizes, int n_in,
                              void* d_out, int out_size, void* d_ws, size_t ws_size,
                              hipStream_t stream)
{
    const float* x   = (const float*)d_in[0];
    const float* wgt = (const float*)d_in[1];
    float* out       = (float*)d_out;

    // y-strips of 2*4 = 8 rows -> 64 strips; grid = 64 x 64 images
    dim3 grid(IMG_H / (2 * ROWS), NIMG, 1);
    conv7x7_kernel<<<grid, 256, 0, stream>>>(x, wgt, out);
}

// Round 8
// 125.344 us; speedup vs baseline: 4.0205x; 4.0205x over previous
//
#include <hip/hip_runtime.h>

// 7x7 conv, stride 1, pad 3, on 64 x 512 x 512 fp32 (single channel).
// out[n,y,x] = sum_{ky,kx} x[n, y+ky-3, x+kx-3] * w[ky,kx]
//
// R7: R4's LDS tile + BANK-SWIZZLED layout. Per-lane-contiguous windows have a
// 16B across-lane stride -> 4-way bank conflict on every LDS access (R4:
// 1.14e7 conflict cycles = ~40% of runtime). Storing float col c at physical
// index c + (c>>5) (1 pad float per 32) rotates each 32-col group by +1 bank,
// spreading the 8-bank pattern over all 32 banks. Swizzled addrs are only
// 4B-aligned -> all LDS traffic is b32/read2 (dword ops, conflict-free).

#define IMG_W 512
#define IMG_H 512
#define NIMG  64
#define TW    256            // output tile width per block
#define TH    16             // output tile height per block
#define HALO  3
#define LDS_W 264            // logical cols: tile col c <-> global x = bx-4+c
#define NF4   (LDS_W / 4)    // 66 float4 per row (staging granularity)
#define LDS_H (TH + 2*HALO)  // 22
#define ROWP  272            // physical row stride: 263 + (263>>5) = 271 -> 272

__device__ __forceinline__ int swz(int c) { return c + (c >> 5); }

__global__ __launch_bounds__(256, 4) void conv7x7_kernel(
    const float* __restrict__ x,
    const float* __restrict__ wgt,
    float* __restrict__ out)
{
    __shared__ float tile[LDS_H * ROWP];   // 23,936 B

    const int tid = threadIdx.x;
    const int bx  = blockIdx.x * TW;
    const int by  = blockIdx.y * TH;
    const int n   = blockIdx.z;

    const float* img = x + (size_t)n * (IMG_W * IMG_H);

    // ---- stage tile: global float4 (guarded, aligned) -> 4 swizzled b32 ----
    for (int i = tid; i < LDS_H * NF4; i += 256) {
        const int r  = i / NF4;
        const int c4 = i - r * NF4;
        const int gy = by - HALO + r;
        const int gx = bx - 4 + c4 * 4;
        float4 v = make_float4(0.f, 0.f, 0.f, 0.f);
        if ((unsigned)gy < IMG_H && (unsigned)gx < IMG_W)
            v = *(const float4*)&img[gy * IMG_W + gx];
        float* rowp = &tile[r * ROWP];
        const int c = c4 * 4;
        rowp[swz(c + 0)] = v.x;
        rowp[swz(c + 1)] = v.y;
        rowp[swz(c + 2)] = v.z;
        rowp[swz(c + 3)] = v.w;
    }

    // ---- weights: wave-uniform -> SGPRs ----
    float w[49];
    #pragma unroll
    for (int i = 0; i < 49; ++i) w[i] = wgt[i];

    __syncthreads();

    // ---- compute: 4x x 4y outputs per thread, 10 swizzled b32 per row ----
    const int tx = tid & 63;
    const int ty = tid >> 6;
    const int lx = tx * 4;     // output x within tile
    const int rbase = ty * 4;

    // needed logical cols per row: c = lx+1 .. lx+10  (t = cc+kx, 0..9)
    int coff[10];
    #pragma unroll
    for (int t = 0; t < 10; ++t) coff[t] = swz(lx + 1 + t);

    float acc[4][4] = {};

    #pragma unroll
    for (int r = 0; r < 10; ++r) {
        const float* rowp = &tile[(rbase + r) * ROWP];
        float row[10];
        #pragma unroll
        for (int t = 0; t < 10; ++t) row[t] = rowp[coff[t]];
        #pragma unroll
        for (int j = 0; j < 4; ++j) {
            const int ky = r - j;
            if (ky >= 0 && ky < 7) {
                #pragma unroll
                for (int kx = 0; kx < 7; ++kx) {
                    const float wv = w[ky * 7 + kx];
                    #pragma unroll
                    for (int cc = 0; cc < 4; ++cc)
                        acc[j][cc] = fmaf(row[cc + kx], wv, acc[j][cc]);
                }
            }
        }
    }

    // ---- store: 4 rows of float4 per thread ----
    float* o = out + (size_t)n * (IMG_W * IMG_H);
    #pragma unroll
    for (int j = 0; j < 4; ++j) {
        float4 v = make_float4(acc[j][0], acc[j][1], acc[j][2], acc[j][3]);
        *(float4*)&o[(size_t)(by + rbase + j) * IMG_W + bx + lx] = v;
    }
}

extern "C" void kernel_launch(void* const* d_in, const int* in_sizes, int n_in,
                              void* d_out, int out_size, void* d_ws, size_t ws_size,
                              hipStream_t stream)
{
    const float* x   = (const float*)d_in[0];
    const float* wgt = (const float*)d_in[1];
    float* out       = (float*)d_out;

    dim3 grid(IMG_W / TW, IMG_H / TH, NIMG);   // 2 x 32 x 64 = 4096 blocks
    conv7x7_kernel<<<grid, 256, 0, stream>>>(x, wgt, out);
}